// Round 3
// baseline (260.633 us; speedup 1.0000x reference)
//
#include <hip/hip_runtime.h>

// Problem constants (fixed by setup_inputs)
#define N_PED 2048
#define NGROUP 64
#define NPG 32        // peds per group
#define HDIM 128
#define DIN 64
#define DDIM 64
#define NHEAD 4
#define TOBS 8

__device__ __forceinline__ float sigm(float x){ return 1.f/(1.f + __expf(-x)); }

// ---------------------------------------------------------------------------
// sentinel fill: if gat_kernel fails to run, absmax ~= 12345 tells us so
// (vs 0.8515 = "ran but produced zeros"). Removed once the pipeline is green.
// ---------------------------------------------------------------------------
__global__ __launch_bounds__(512) void fill_kernel(float* __restrict__ out) {
    out[blockIdx.x * 512 + threadIdx.x] = 12345.0f;
}

// ---------------------------------------------------------------------------
// prep: v[h] = w[h] @ a2, w1[h] = w[h] @ a1  (score projections; 1 block)
// VW layout: [0:512) = V[h][f], [512:1024) = W1[h][f]
// ---------------------------------------------------------------------------
__global__ __launch_bounds__(512) void prep_kernel(const float* __restrict__ gat_w,
                                                   const float* __restrict__ gat_a,
                                                   float* __restrict__ VW) {
    __shared__ float sa[2*HDIM];
    const int tid = threadIdx.x;
    if (tid < 2*HDIM) sa[tid] = gat_a[tid];
    __syncthreads();
    const int h = tid >> 7, f = tid & 127;
    const float* row = gat_w + (h*HDIM + f)*HDIM;   // w[h][f][:]
    float v = 0.f, w1 = 0.f;
    for (int o = 0; o < HDIM; ++o) {
        float wv = row[o];
        v  += wv * sa[HDIM + o];
        w1 += wv * sa[o];
    }
    VW[tid]       = v;
    VW[512 + tid] = w1;
}

// ---------------------------------------------------------------------------
// LSTM: 256 blocks x 512 threads, 8 peds per block. Embedding fused.
// Thread tid owns gate-row r=tid for all 8 peds. vec = [x(64) | h(128)] in LDS.
// ---------------------------------------------------------------------------
__global__ __launch_bounds__(512) void lstm_kernel(
    const float* __restrict__ obs,   // (8,2048,2)
    const float* __restrict__ h0,    // (2048,128)
    const float* __restrict__ c0,
    const float* __restrict__ W_emb, // (2,64)
    const float* __restrict__ b_emb, // (64)
    const float* __restrict__ W_ih,  // (512,64)
    const float* __restrict__ W_hh,  // (512,128)
    const float* __restrict__ b_ih,  // (512)
    const float* __restrict__ b_hh,  // (512)
    float* __restrict__ AH,          // (2048,128) fp32 out
    float* __restrict__ TAH)         // tanh(AH)
{
    __shared__ float vecs[8][192];      // [x | h] per ped
    __shared__ float gatesL[8][512];
    __shared__ float WembL[128];
    __shared__ float bembL[64];

    const int tid  = threadIdx.x;
    const int ped0 = blockIdx.x * 8;

    if (tid < 128) WembL[tid] = W_emb[tid];
    else if (tid < 192) bembL[tid-128] = b_emb[tid-128];

    // stage h0 into vecs[:,64:192]
    for (int q = tid; q < 1024; q += 512) {
        int p = q >> 7, u = q & 127;
        vecs[p][64+u] = h0[(ped0+p)*HDIM + u];
    }
    // c state: thread owns (pu, u0) and (pu, u0+64)
    const int pu = tid >> 6, u0 = tid & 63;
    float cc0 = c0[(ped0+pu)*HDIM + u0];
    float cc1 = c0[(ped0+pu)*HDIM + u0 + 64];

    const int r = tid;
    const float bsum = b_ih[r] + b_hh[r];
    const float4* wih = reinterpret_cast<const float4*>(W_ih + r*DIN);   // 16 chunks
    const float4* whh = reinterpret_cast<const float4*>(W_hh + r*HDIM);  // 32 chunks

    __syncthreads();

    for (int t = 0; t < TOBS; ++t) {
        // stage x_t (relu embed) into vecs[:,0:64]
        {
            int p = tid >> 6, d = tid & 63;
            const float2 ob = reinterpret_cast<const float2*>(obs)[(size_t)(t*N_PED + ped0 + p)];
            float x = ob.x*WembL[d] + ob.y*WembL[64+d] + bembL[d];
            vecs[p][d] = fmaxf(x, 0.f);
        }
        if (t > 0) {
            // apply gate update from step t-1, write new h into vecs
            const float* gp = &gatesL[pu][0];
            {
                float gi = gp[u0], gf = gp[128+u0], gg = gp[256+u0], go = gp[384+u0];
                cc0 = sigm(gf)*cc0 + sigm(gi)*tanhf(gg);
                vecs[pu][64+u0] = sigm(go)*tanhf(cc0);
            }
            {
                int u = u0 + 64;
                float gi = gp[u], gf = gp[128+u], gg = gp[256+u], go = gp[384+u];
                cc1 = sigm(gf)*cc1 + sigm(gi)*tanhf(gg);
                vecs[pu][64+u] = sigm(go)*tanhf(cc1);
            }
        }
        __syncthreads();

        // gates(t): row r for 8 peds
        float acc[8];
        #pragma unroll
        for (int p = 0; p < 8; ++p) acc[p] = bsum;

        #pragma unroll
        for (int c = 0; c < 16; ++c) {          // W_ih part, k = 4c..4c+3
            float4 w = wih[c];
            #pragma unroll
            for (int p = 0; p < 8; ++p) {
                float4 v = *reinterpret_cast<const float4*>(&vecs[p][c*4]);
                acc[p] += w.x*v.x + w.y*v.y + w.z*v.z + w.w*v.w;
            }
        }
        #pragma unroll
        for (int c = 0; c < 32; ++c) {          // W_hh part, h idx = 4c..4c+3
            float4 w = whh[c];
            #pragma unroll
            for (int p = 0; p < 8; ++p) {
                float4 v = *reinterpret_cast<const float4*>(&vecs[p][64 + c*4]);
                acc[p] += w.x*v.x + w.y*v.y + w.z*v.z + w.w*v.w;
            }
        }
        #pragma unroll
        for (int p = 0; p < 8; ++p) gatesL[p][r] = acc[p];
        __syncthreads();
    }

    // final update (t=7) -> AH / TAH
    {
        const float* gp = &gatesL[pu][0];
        {
            float gi = gp[u0], gf = gp[128+u0], gg = gp[256+u0], go = gp[384+u0];
            cc0 = sigm(gf)*cc0 + sigm(gi)*tanhf(gg);
            float h = sigm(go)*tanhf(cc0);
            AH [(ped0+pu)*HDIM + u0] = h;
            TAH[(ped0+pu)*HDIM + u0] = tanhf(h);
        }
        {
            int u = u0 + 64;
            float gi = gp[u], gf = gp[128+u], gg = gp[256+u], go = gp[384+u];
            cc1 = sigm(gf)*cc1 + sigm(gi)*tanhf(gg);
            float h = sigm(go)*tanhf(cc1);
            AH [(ped0+pu)*HDIM + u] = h;
            TAH[(ped0+pu)*HDIM + u] = tanhf(h);
        }
    }
}

// ---------------------------------------------------------------------------
// GAT: 512 blocks x 256 threads. Block = (group g, 4 rows i0..i0+3).
// score[h][i][k] = ah[i]·w1[h] + h_other[i][k]·v[h]; out by linearity:
// out[i] = relu( (1/4) sum_h (sum_k alpha*h_other) @ w[h] ) + bias
// ---------------------------------------------------------------------------
__global__ __launch_bounds__(256) void gat_kernel(
    const float* __restrict__ AH, const float* __restrict__ TAH,
    const float* __restrict__ VW,
    const float* __restrict__ ghs,    // goal_hidden_state (2048,128)
    const float* __restrict__ goal,   // (2048,2)
    const float* __restrict__ action, // (2048,2)
    const float* __restrict__ W_dist, // (8,64)
    const float* __restrict__ b_dist, // (64)
    const float* __restrict__ W_gate, // (64,128)
    const float* __restrict__ b_gate, // (128)
    const float* __restrict__ gat_w,  // (4,1,128,128)
    const float* __restrict__ gat_bias, // (128)
    float* __restrict__ out)          // (2048,128)
{
    __shared__ float sTAH[NPG][HDIM];     // 16384
    __shared__ float sAHr[4][HDIM];       //  2048  (rows i0..i0+3 only)
    __shared__ float sGH[4][HDIM];        //  2048
    __shared__ float sAC[NPG][2];         //   256
    __shared__ float sGL[NPG][2];         //   256
    __shared__ float sWd[8][DDIM];        //  2048
    __shared__ float sbd[DDIM];           //   256
    __shared__ float sbg[HDIM];           //   512
    __shared__ float sgb[HDIM];           //   512
    __shared__ float sV[NHEAD][HDIM];     //  2048
    __shared__ float st1[NPG][DDIM];      //  8192
    __shared__ float sGA[NPG][HDIM];      // 16384
    __shared__ float sPj[NPG][NHEAD];     //   512
    __shared__ float sMisc[12];           //    48
    __shared__ float sAl[NHEAD][NPG+1];   //   528
    __shared__ float sU[NHEAD][HDIM][4];  //  8192  [h][f][row]
    __shared__ float sPart[4][HDIM];      //  2048

    const int tid = threadIdx.x;
    const int g   = blockIdx.x >> 3;
    const int i0  = (blockIdx.x & 7) * 4;
    const int p0  = g * NPG;
    const int f_t = tid & 127;

    // ---- stage group data ----
    {
        const float4* t4 = reinterpret_cast<const float4*>(TAH + (size_t)p0*HDIM);
        for (int q = tid; q < 1024; q += 256)
            reinterpret_cast<float4*>(&sTAH[0][0])[q] = t4[q];
        const float4* a4 = reinterpret_cast<const float4*>(AH + (size_t)(p0 + i0)*HDIM);
        if (tid < 128) reinterpret_cast<float4*>(&sAHr[0][0])[tid] = a4[tid];
        for (int q = tid; q < 512; q += 256) {
            int rr = q >> 7, u = q & 127;
            sGH[rr][u] = ghs[(size_t)(p0 + i0 + rr)*HDIM + u];
            (&sWd[0][0])[q] = W_dist[q];
            (&sV[0][0])[q]  = VW[q];
        }
        if (tid < NPG) {
            const float2 ac = reinterpret_cast<const float2*>(action)[p0+tid];
            const float2 gl = reinterpret_cast<const float2*>(goal)[p0+tid];
            sAC[tid][0] = ac.x; sAC[tid][1] = ac.y;
            sGL[tid][0] = gl.x; sGL[tid][1] = gl.y;
        }
        if (tid < 64)  sbd[tid] = b_dist[tid];
        if (tid >= 64 && tid < 192) sbg[tid-64] = b_gate[tid-64];
        if (tid >= 192) {
            int o = tid - 192;
            sgb[o]    = gat_bias[o];
            sgb[o+64] = gat_bias[o+64];
        }
    }
    __syncthreads();

    // W_gate column f_t in registers
    float wgcol[DDIM];
    #pragma unroll
    for (int k = 0; k < DDIM; ++k)
        wgcol[k] = W_gate[k*HDIM + f_t];

    // ---- per-row pipeline ----
    for (int r = 0; r < 4; ++r) {
        const int i = i0 + r;

        // (a) t1[j][k] = relu(dist(i,j) @ W_dist + b_dist)
        {
            int k = tid & 63, jg = tid >> 6;
            float base = sAC[i][0]*sWd[0][k] + sAC[i][1]*sWd[1][k]
                       + sGL[i][0]*sWd[2][k] + sGL[i][1]*sWd[3][k] + sbd[k];
            #pragma unroll
            for (int jj = 0; jj < 8; ++jj) {
                int j = jg*8 + jj;
                float v = base + sAC[j][0]*sWd[4][k] + sAC[j][1]*sWd[5][k]
                               + sGL[j][0]*sWd[6][k] + sGL[j][1]*sWd[7][k];
                st1[j][k] = fmaxf(v, 0.f);
            }
        }
        __syncthreads();

        // (b) gate_action[j][f] = sigmoid(t1[j]@W_gate + b_gate)[f] * tanh(ah[j])[f]
        {
            int jh = tid >> 7;
            for (int jj = 0; jj < 16; ++jj) {
                int j = jh*16 + jj;
                float s = sbg[f_t];
                const float4* t4 = reinterpret_cast<const float4*>(&st1[j][0]);
                #pragma unroll
                for (int kc = 0; kc < 16; ++kc) {
                    float4 tv = t4[kc];
                    s += tv.x*wgcol[kc*4] + tv.y*wgcol[kc*4+1]
                       + tv.z*wgcol[kc*4+2] + tv.w*wgcol[kc*4+3];
                }
                float gate = sigm(s);
                sGA[j][f_t] = gate * sTAH[j][f_t];
            }
        }
        __syncthreads();

        // (c) projections onto v[h] / w1[h]
        if (tid < 128) {
            int j = tid >> 2, h = tid & 3;
            float s = 0.f;
            for (int ff = 0; ff < HDIM; ++ff) {
                int f = (ff + tid) & 127;
                s += sGA[j][f] * sV[h][f];
            }
            sPj[j][h] = s;
        } else if (tid < 140) {
            int w = tid - 128; int h = w & 3; int which = w >> 2; // 0:p0 1:pd 2:sa
            const float* vv  = (which == 2) ? (VW + 512 + h*HDIM) : &sV[h][0];
            const float* src = (which == 1) ? &sGH[r][0] : &sAHr[r][0];
            float s = 0.f;
            for (int f = 0; f < HDIM; ++f) s += src[f]*vv[f];
            sMisc[w] = s;
        }
        __syncthreads();

        // (d) scores -> leaky_relu -> softmax over k (33)
        if (tid < 4) {
            int h = tid;
            float sa_ = sMisc[8+h], pp0 = sMisc[h], ppd = sMisc[4+h];
            float mx = -1e30f;
            for (int k = 0; k < NPG+1; ++k) {
                float x;
                if (k == 0) x = sa_ + pp0;
                else { int j = k-1; x = sa_ + ((j == i) ? ppd : sPj[j][h]); }
                x = (x < 0.f) ? 0.2f*x : x;
                sAl[h][k] = x;
                mx = fmaxf(mx, x);
            }
            float sum = 0.f;
            for (int k = 0; k < NPG+1; ++k) {
                float e = __expf(sAl[h][k] - mx);
                sAl[h][k] = e; sum += e;
            }
            float inv = 1.f/sum;
            for (int k = 0; k < NPG+1; ++k) sAl[h][k] *= inv;
        }
        __syncthreads();

        // (e) u[h][f] = sum_k alpha * h_other[k][f]
        {
            int hh = tid >> 7;
            #pragma unroll
            for (int q = 0; q < 2; ++q) {
                int h = hh*2 + q;
                float u = sAl[h][0]*sAHr[r][f_t] + sAl[h][i+1]*sGH[r][f_t];
                for (int j = 0; j < NPG; ++j) {
                    if (j != i) u += sAl[h][j+1]*sGA[j][f_t];
                }
                sU[h][f_t][r] = u;
            }
        }
        __syncthreads();
    }

    // (f) out[i] = relu( (1/4) sum_h u[h] @ w[h] ) + gat_bias  (all 4 rows)
    float acc[4] = {0.f, 0.f, 0.f, 0.f};
    {
        int o = f_t, fh = tid >> 7;
        #pragma unroll
        for (int h = 0; h < NHEAD; ++h) {
            const float* wp = gat_w + h*HDIM*HDIM + (fh*64)*HDIM + o;
            for (int f = 0; f < 64; ++f) {
                float wv = wp[f*HDIM];
                float4 uv = *reinterpret_cast<const float4*>(&sU[h][fh*64 + f][0]);
                acc[0] += uv.x*wv; acc[1] += uv.y*wv;
                acc[2] += uv.z*wv; acc[3] += uv.w*wv;
            }
        }
        if (fh == 1) {
            sPart[0][o]=acc[0]; sPart[1][o]=acc[1]; sPart[2][o]=acc[2]; sPart[3][o]=acc[3];
        }
    }
    __syncthreads();
    if (tid < 128) {
        int o = tid;
        #pragma unroll
        for (int rr = 0; rr < 4; ++rr) {
            float tot = (acc[rr] + sPart[rr][o]) * 0.25f;
            float val = fmaxf(tot, 0.f) + sgb[o];
            out[(size_t)(p0 + i0 + rr)*HDIM + o] = val;
        }
    }
}

// ---------------------------------------------------------------------------
extern "C" void kernel_launch(void* const* d_in, const int* in_sizes, int n_in,
                              void* d_out, int out_size, void* d_ws, size_t ws_size,
                              hipStream_t stream) {
    const float* obs      = (const float*)d_in[0];
    const float* ghs      = (const float*)d_in[1];
    const float* goal     = (const float*)d_in[2];
    const float* action   = (const float*)d_in[3];
    const float* h0       = (const float*)d_in[4];
    const float* c0       = (const float*)d_in[5];
    const float* W_emb    = (const float*)d_in[6];
    const float* b_emb    = (const float*)d_in[7];
    const float* W_ih     = (const float*)d_in[8];
    const float* W_hh     = (const float*)d_in[9];
    const float* b_ih     = (const float*)d_in[10];
    const float* b_hh     = (const float*)d_in[11];
    const float* W_dist   = (const float*)d_in[12];
    const float* b_dist   = (const float*)d_in[13];
    const float* W_gate   = (const float*)d_in[14];
    const float* b_gate   = (const float*)d_in[15];
    const float* gat_w    = (const float*)d_in[16];
    const float* gat_a    = (const float*)d_in[17];
    const float* gat_bias = (const float*)d_in[18];

    float* ws  = (float*)d_ws;
    float* AH  = ws;                 // 2048*128
    float* TAH = ws + 262144;        // 2048*128
    float* VW  = ws + 524288;        // 1024
    float* out = (float*)d_out;

    hipLaunchKernelGGL(fill_kernel, dim3(512), dim3(512), 0, stream, out);
    hipLaunchKernelGGL(prep_kernel, dim3(1),   dim3(512), 0, stream, gat_w, gat_a, VW);
    hipLaunchKernelGGL(lstm_kernel, dim3(256), dim3(512), 0, stream,
                       obs, h0, c0, W_emb, b_emb, W_ih, W_hh, b_ih, b_hh, AH, TAH);
    hipLaunchKernelGGL(gat_kernel,  dim3(512), dim3(256), 0, stream,
                       AH, TAH, VW, ghs, goal, action,
                       W_dist, b_dist, W_gate, b_gate, gat_w, gat_bias, out);
}

// Round 4
// 193.384 us; speedup vs baseline: 1.3477x; 1.3477x over previous
//
#include <hip/hip_runtime.h>

// Problem constants (fixed by setup_inputs)
#define N_PED 2048
#define NGROUP 64
#define NPG 32        // peds per group
#define HDIM 128
#define DIN 64
#define DDIM 64
#define NHEAD 4
#define TOBS 8

#define KDIM 192      // [x(64) | h(128)]
#define KPAD 216      // +24 bf16 pad: 432B row stride -> 2-way LDS aliasing (free)

typedef __attribute__((ext_vector_type(8))) short bf16x8;
typedef __attribute__((ext_vector_type(4))) float f32x4;

__device__ __forceinline__ float sigm(float x){ return 1.f/(1.f + __expf(-x)); }
__device__ __forceinline__ float tanh_fast(float x){
    // tanh(x) = 1 - 2/(e^{2x}+1)
    return 1.f - 2.f/(__expf(2.f*x) + 1.f);
}
__device__ __forceinline__ short f2bf(float f){
    unsigned u = __float_as_uint(f);
    unsigned r = (u + 0x7fffu + ((u >> 16) & 1u)) >> 16;   // RNE
    return (short)r;
}

// ---------------------------------------------------------------------------
// prep: V[h][f] = w[h][f]·a2, W1[h][f] = w[h][f]·a1.  16 blocks x 256 thr,
// coalesced row reads (8 threads x 16 floats per row), LDS reduction.
// VW layout: [0:512) = V, [512:1024) = W1
// ---------------------------------------------------------------------------
__global__ __launch_bounds__(256) void prep_kernel(const float* __restrict__ gat_w,
                                                   const float* __restrict__ gat_a,
                                                   float* __restrict__ VW) {
    __shared__ float sa[2*HDIM];
    __shared__ float red[32][8][2];
    const int tid = threadIdx.x;
    if (tid < 256) sa[tid] = gat_a[tid];
    __syncthreads();
    const int rl = tid >> 3, ch = tid & 7;
    const int row = blockIdx.x*32 + rl;          // row = h*128 + f
    const float* rp = gat_w + (size_t)row*HDIM + ch*16;
    float v = 0.f, w1 = 0.f;
    #pragma unroll
    for (int e = 0; e < 16; ++e) {
        float wv = rp[e];
        v  += wv * sa[HDIM + ch*16 + e];
        w1 += wv * sa[ch*16 + e];
    }
    red[rl][ch][0] = v; red[rl][ch][1] = w1;
    __syncthreads();
    if (ch == 0) {
        float sv = 0.f, sw = 0.f;
        #pragma unroll
        for (int e = 0; e < 8; ++e) { sv += red[rl][e][0]; sw += red[rl][e][1]; }
        VW[row]       = sv;
        VW[512 + row] = sw;
    }
}

// ---------------------------------------------------------------------------
// LSTM via MFMA bf16: 128 blocks x 512 thr, 16 peds/block.
// Per t: gates[16x512] = X[16x192] @ Wcat[192x512] + bias, via
// mfma_f32_16x16x32_bf16. Wave w owns n-tiles {w, w+8, w+16, w+24} so each
// lane's 4 accumulators are the i/f/g/o gates of unit u = 16w+(lane&15) for
// peds q*4+{0..3} -> LSTM cell update entirely in registers. B-fragments
// (bf16 weights) are converted once and live in 96 VGPRs across all 8 steps.
// X (bf16) lives in LDS [16][KPAD]; h written back as bf16 each step.
// ---------------------------------------------------------------------------
__global__ __launch_bounds__(512) void lstm_kernel(
    const float* __restrict__ obs,   // (8,2048,2)
    const float* __restrict__ h0,    // (2048,128)
    const float* __restrict__ c0,
    const float* __restrict__ W_emb, // (2,64)
    const float* __restrict__ b_emb, // (64)
    const float* __restrict__ W_ih,  // (512,64)
    const float* __restrict__ W_hh,  // (512,128)
    const float* __restrict__ b_ih,  // (512)
    const float* __restrict__ b_hh,  // (512)
    float* __restrict__ AH,          // (2048,128) fp32 out
    float* __restrict__ TAH)         // tanh(AH)
{
    __shared__ short Xl[16][KPAD];   // bf16 [x | h]
    __shared__ float sEmb[192];      // W_emb(128) | b_emb(64)

    const int tid  = threadIdx.x;
    const int ped0 = blockIdx.x * 16;
    const int w    = tid >> 6;        // wave 0..7
    const int lane = tid & 63;
    const int q    = lane >> 4;       // 0..3
    const int ln   = lane & 15;
    const int u    = w*16 + ln;       // hidden unit 0..127 owned by this lane

    if (tid < 192) sEmb[tid] = (tid < 128) ? W_emb[tid] : b_emb[tid - 128];

    // ---- B fragments: Wcat[k][n], n = 128*idx + u, k = kt*32 + q*8 + j ----
    // Wcat[k][n] = (k<64) ? W_ih[n][k] : W_hh[n][k-64]
    bf16x8 bfr[4][6];
    #pragma unroll
    for (int idx = 0; idx < 4; ++idx) {
        const int n = idx*128 + u;
        #pragma unroll
        for (int kt = 0; kt < 6; ++kt) {
            const float* src = (kt < 2) ? (W_ih + (size_t)n*DIN  + kt*32 + q*8)
                                        : (W_hh + (size_t)n*HDIM + (kt-2)*32 + q*8);
            bf16x8 b;
            #pragma unroll
            for (int j = 0; j < 8; ++j) b[j] = f2bf(src[j]);
            bfr[idx][kt] = b;
        }
    }

    // bias per column (same for all 4 accumulator rows)
    float bsv[4];
    #pragma unroll
    for (int idx = 0; idx < 4; ++idx) {
        const int n = idx*128 + u;
        bsv[idx] = b_ih[n] + b_hh[n];
    }

    // c state: lane owns (ped q*4+reg, unit u)
    float c_st[4];
    #pragma unroll
    for (int reg = 0; reg < 4; ++reg)
        c_st[reg] = c0[(size_t)(ped0 + q*4 + reg)*HDIM + u];

    // ---- stage h0 (bf16) and x_0 into Xl ----
    #pragma unroll
    for (int reg = 0; reg < 4; ++reg) {
        const int pl = q*4 + reg;
        Xl[pl][64 + u] = f2bf(h0[(size_t)(ped0 + pl)*HDIM + u]);
    }
    {   // x_0 embed: thread -> (ped = tid>>5, d0 = (tid&31)*2)
        const int ped = tid >> 5, d0 = (tid & 31)*2;
        const float2 ob = reinterpret_cast<const float2*>(obs)[(size_t)(0*N_PED + ped0 + ped)];
        float x0 = fmaxf(ob.x*sEmb[d0]   + ob.y*sEmb[64+d0]   + sEmb[128+d0],   0.f);
        float x1 = fmaxf(ob.x*sEmb[d0+1] + ob.y*sEmb[64+d0+1] + sEmb[128+d0+1], 0.f);
        unsigned pk = (unsigned)(unsigned short)f2bf(x0) | ((unsigned)(unsigned short)f2bf(x1) << 16);
        *reinterpret_cast<unsigned*>(&Xl[ped][d0]) = pk;
    }
    __syncthreads();

    float hval[4];
    for (int t = 0; t < TOBS; ++t) {
        // A fragments: X[m=ln][k = kt*32 + q*8 + j]
        bf16x8 afr[6];
        #pragma unroll
        for (int kt = 0; kt < 6; ++kt)
            afr[kt] = *reinterpret_cast<const bf16x8*>(&Xl[ln][kt*32 + q*8]);

        f32x4 acc[4];
        #pragma unroll
        for (int idx = 0; idx < 4; ++idx) {
            f32x4 a = { bsv[idx], bsv[idx], bsv[idx], bsv[idx] };
            #pragma unroll
            for (int kt = 0; kt < 6; ++kt)
                a = __builtin_amdgcn_mfma_f32_16x16x32_bf16(afr[kt], bfr[idx][kt], a, 0, 0, 0);
            acc[idx] = a;
        }

        // cell update: acc[0]=i, acc[1]=f, acc[2]=g, acc[3]=o ; row = q*4+reg
        #pragma unroll
        for (int reg = 0; reg < 4; ++reg) {
            float gi = acc[0][reg], gf = acc[1][reg], gg = acc[2][reg], go = acc[3][reg];
            float c = sigm(gf)*c_st[reg] + sigm(gi)*tanh_fast(gg);
            c_st[reg] = c;
            hval[reg] = sigm(go)*tanh_fast(c);
        }
        __syncthreads();   // all waves done reading Xl

        if (t < TOBS-1) {
            #pragma unroll
            for (int reg = 0; reg < 4; ++reg)
                Xl[q*4 + reg][64 + u] = f2bf(hval[reg]);
            {   // x_{t+1} embed
                const int ped = tid >> 5, d0 = (tid & 31)*2;
                const float2 ob = reinterpret_cast<const float2*>(obs)[(size_t)((t+1)*N_PED + ped0 + ped)];
                float x0 = fmaxf(ob.x*sEmb[d0]   + ob.y*sEmb[64+d0]   + sEmb[128+d0],   0.f);
                float x1 = fmaxf(ob.x*sEmb[d0+1] + ob.y*sEmb[64+d0+1] + sEmb[128+d0+1], 0.f);
                unsigned pk = (unsigned)(unsigned short)f2bf(x0) | ((unsigned)(unsigned short)f2bf(x1) << 16);
                *reinterpret_cast<unsigned*>(&Xl[ped][d0]) = pk;
            }
            __syncthreads();
        }
    }

    // final h -> AH / TAH (fp32)
    #pragma unroll
    for (int reg = 0; reg < 4; ++reg) {
        const size_t off = (size_t)(ped0 + q*4 + reg)*HDIM + u;
        AH[off]  = hval[reg];
        TAH[off] = tanh_fast(hval[reg]);
    }
}

// ---------------------------------------------------------------------------
// GAT: 512 blocks x 256 threads. Block = (group g, 4 rows i0..i0+3).
// score[h][i][k] = ah[i]·w1[h] + h_other[i][k]·v[h]; out by linearity:
// out[i] = relu( (1/4) sum_h (sum_k alpha*h_other) @ w[h] ) + bias
// ---------------------------------------------------------------------------
__global__ __launch_bounds__(256) void gat_kernel(
    const float* __restrict__ AH, const float* __restrict__ TAH,
    const float* __restrict__ VW,
    const float* __restrict__ ghs,    // goal_hidden_state (2048,128)
    const float* __restrict__ goal,   // (2048,2)
    const float* __restrict__ action, // (2048,2)
    const float* __restrict__ W_dist, // (8,64)
    const float* __restrict__ b_dist, // (64)
    const float* __restrict__ W_gate, // (64,128)
    const float* __restrict__ b_gate, // (128)
    const float* __restrict__ gat_w,  // (4,1,128,128)
    const float* __restrict__ gat_bias, // (128)
    float* __restrict__ out)          // (2048,128)
{
    __shared__ float sTAH[NPG][HDIM];     // 16384
    __shared__ float sAHr[4][HDIM];       //  2048  (rows i0..i0+3 only)
    __shared__ float sGH[4][HDIM];        //  2048
    __shared__ float sAC[NPG][2];         //   256
    __shared__ float sGL[NPG][2];         //   256
    __shared__ float sWd[8][DDIM];        //  2048
    __shared__ float sbd[DDIM];           //   256
    __shared__ float sbg[HDIM];           //   512
    __shared__ float sgb[HDIM];           //   512
    __shared__ float sV[NHEAD][HDIM];     //  2048
    __shared__ float st1[NPG][DDIM];      //  8192
    __shared__ float sGA[NPG][HDIM];      // 16384
    __shared__ float sPj[NPG][NHEAD];     //   512
    __shared__ float sMisc[12];           //    48
    __shared__ float sAl[NHEAD][NPG+1];   //   528
    __shared__ float sU[NHEAD][HDIM][4];  //  8192  [h][f][row]
    __shared__ float sPart[4][HDIM];      //  2048

    const int tid = threadIdx.x;
    const int g   = blockIdx.x >> 3;
    const int i0  = (blockIdx.x & 7) * 4;
    const int p0  = g * NPG;
    const int f_t = tid & 127;

    // ---- stage group data ----
    {
        const float4* t4 = reinterpret_cast<const float4*>(TAH + (size_t)p0*HDIM);
        for (int q = tid; q < 1024; q += 256)
            reinterpret_cast<float4*>(&sTAH[0][0])[q] = t4[q];
        const float4* a4 = reinterpret_cast<const float4*>(AH + (size_t)(p0 + i0)*HDIM);
        if (tid < 128) reinterpret_cast<float4*>(&sAHr[0][0])[tid] = a4[tid];
        for (int q = tid; q < 512; q += 256) {
            int rr = q >> 7, u = q & 127;
            sGH[rr][u] = ghs[(size_t)(p0 + i0 + rr)*HDIM + u];
            (&sWd[0][0])[q] = W_dist[q];
            (&sV[0][0])[q]  = VW[q];
        }
        if (tid < NPG) {
            const float2 ac = reinterpret_cast<const float2*>(action)[p0+tid];
            const float2 gl = reinterpret_cast<const float2*>(goal)[p0+tid];
            sAC[tid][0] = ac.x; sAC[tid][1] = ac.y;
            sGL[tid][0] = gl.x; sGL[tid][1] = gl.y;
        }
        if (tid < 64)  sbd[tid] = b_dist[tid];
        if (tid >= 64 && tid < 192) sbg[tid-64] = b_gate[tid-64];
        if (tid >= 192) {
            int o = tid - 192;
            sgb[o]    = gat_bias[o];
            sgb[o+64] = gat_bias[o+64];
        }
    }
    __syncthreads();

    // W_gate column f_t in registers
    float wgcol[DDIM];
    #pragma unroll
    for (int k = 0; k < DDIM; ++k)
        wgcol[k] = W_gate[k*HDIM + f_t];

    // ---- per-row pipeline ----
    for (int r = 0; r < 4; ++r) {
        const int i = i0 + r;

        // (a) t1[j][k] = relu(dist(i,j) @ W_dist + b_dist)
        {
            int k = tid & 63, jg = tid >> 6;
            float base = sAC[i][0]*sWd[0][k] + sAC[i][1]*sWd[1][k]
                       + sGL[i][0]*sWd[2][k] + sGL[i][1]*sWd[3][k] + sbd[k];
            #pragma unroll
            for (int jj = 0; jj < 8; ++jj) {
                int j = jg*8 + jj;
                float v = base + sAC[j][0]*sWd[4][k] + sAC[j][1]*sWd[5][k]
                               + sGL[j][0]*sWd[6][k] + sGL[j][1]*sWd[7][k];
                st1[j][k] = fmaxf(v, 0.f);
            }
        }
        __syncthreads();

        // (b) gate_action[j][f] = sigmoid(t1[j]@W_gate + b_gate)[f] * tanh(ah[j])[f]
        {
            int jh = tid >> 7;
            for (int jj = 0; jj < 16; ++jj) {
                int j = jh*16 + jj;
                float s = sbg[f_t];
                const float4* t4 = reinterpret_cast<const float4*>(&st1[j][0]);
                #pragma unroll
                for (int kc = 0; kc < 16; ++kc) {
                    float4 tv = t4[kc];
                    s += tv.x*wgcol[kc*4] + tv.y*wgcol[kc*4+1]
                       + tv.z*wgcol[kc*4+2] + tv.w*wgcol[kc*4+3];
                }
                float gate = sigm(s);
                sGA[j][f_t] = gate * sTAH[j][f_t];
            }
        }
        __syncthreads();

        // (c) projections onto v[h] / w1[h]
        if (tid < 128) {
            int j = tid >> 2, h = tid & 3;
            float s = 0.f;
            for (int ff = 0; ff < HDIM; ++ff) {
                int f = (ff + tid) & 127;
                s += sGA[j][f] * sV[h][f];
            }
            sPj[j][h] = s;
        } else if (tid < 140) {
            int w = tid - 128; int h = w & 3; int which = w >> 2; // 0:p0 1:pd 2:sa
            const float* vv  = (which == 2) ? (VW + 512 + h*HDIM) : &sV[h][0];
            const float* src = (which == 1) ? &sGH[r][0] : &sAHr[r][0];
            float s = 0.f;
            for (int f = 0; f < HDIM; ++f) s += src[f]*vv[f];
            sMisc[w] = s;
        }
        __syncthreads();

        // (d) scores -> leaky_relu -> softmax over k (33)
        if (tid < 4) {
            int h = tid;
            float sa_ = sMisc[8+h], pp0 = sMisc[h], ppd = sMisc[4+h];
            float mx = -1e30f;
            for (int k = 0; k < NPG+1; ++k) {
                float x;
                if (k == 0) x = sa_ + pp0;
                else { int j = k-1; x = sa_ + ((j == i) ? ppd : sPj[j][h]); }
                x = (x < 0.f) ? 0.2f*x : x;
                sAl[h][k] = x;
                mx = fmaxf(mx, x);
            }
            float sum = 0.f;
            for (int k = 0; k < NPG+1; ++k) {
                float e = __expf(sAl[h][k] - mx);
                sAl[h][k] = e; sum += e;
            }
            float inv = 1.f/sum;
            for (int k = 0; k < NPG+1; ++k) sAl[h][k] *= inv;
        }
        __syncthreads();

        // (e) u[h][f] = sum_k alpha * h_other[k][f]
        {
            int hh = tid >> 7;
            #pragma unroll
            for (int q = 0; q < 2; ++q) {
                int h = hh*2 + q;
                float u = sAl[h][0]*sAHr[r][f_t] + sAl[h][i+1]*sGH[r][f_t];
                for (int j = 0; j < NPG; ++j) {
                    if (j != i) u += sAl[h][j+1]*sGA[j][f_t];
                }
                sU[h][f_t][r] = u;
            }
        }
        __syncthreads();
    }

    // (f) out[i] = relu( (1/4) sum_h u[h] @ w[h] ) + gat_bias  (all 4 rows)
    float acc[4] = {0.f, 0.f, 0.f, 0.f};
    {
        int o = f_t, fh = tid >> 7;
        #pragma unroll
        for (int h = 0; h < NHEAD; ++h) {
            const float* wp = gat_w + h*HDIM*HDIM + (fh*64)*HDIM + o;
            for (int f = 0; f < 64; ++f) {
                float wv = wp[f*HDIM];
                float4 uv = *reinterpret_cast<const float4*>(&sU[h][fh*64 + f][0]);
                acc[0] += uv.x*wv; acc[1] += uv.y*wv;
                acc[2] += uv.z*wv; acc[3] += uv.w*wv;
            }
        }
        if (fh == 1) {
            sPart[0][o]=acc[0]; sPart[1][o]=acc[1]; sPart[2][o]=acc[2]; sPart[3][o]=acc[3];
        }
    }
    __syncthreads();
    if (tid < 128) {
        int o = tid;
        #pragma unroll
        for (int rr = 0; rr < 4; ++rr) {
            float tot = (acc[rr] + sPart[rr][o]) * 0.25f;
            float val = fmaxf(tot, 0.f) + sgb[o];
            out[(size_t)(p0 + i0 + rr)*HDIM + o] = val;
        }
    }
}

// ---------------------------------------------------------------------------
extern "C" void kernel_launch(void* const* d_in, const int* in_sizes, int n_in,
                              void* d_out, int out_size, void* d_ws, size_t ws_size,
                              hipStream_t stream) {
    const float* obs      = (const float*)d_in[0];
    const float* ghs      = (const float*)d_in[1];
    const float* goal     = (const float*)d_in[2];
    const float* action   = (const float*)d_in[3];
    const float* h0       = (const float*)d_in[4];
    const float* c0       = (const float*)d_in[5];
    const float* W_emb    = (const float*)d_in[6];
    const float* b_emb    = (const float*)d_in[7];
    const float* W_ih     = (const float*)d_in[8];
    const float* W_hh     = (const float*)d_in[9];
    const float* b_ih     = (const float*)d_in[10];
    const float* b_hh     = (const float*)d_in[11];
    const float* W_dist   = (const float*)d_in[12];
    const float* b_dist   = (const float*)d_in[13];
    const float* W_gate   = (const float*)d_in[14];
    const float* b_gate   = (const float*)d_in[15];
    const float* gat_w    = (const float*)d_in[16];
    const float* gat_a    = (const float*)d_in[17];
    const float* gat_bias = (const float*)d_in[18];

    float* ws  = (float*)d_ws;
    float* AH  = ws;                 // 2048*128
    float* TAH = ws + 262144;        // 2048*128
    float* VW  = ws + 524288;        // 1024
    float* out = (float*)d_out;

    hipLaunchKernelGGL(prep_kernel, dim3(16),  dim3(256), 0, stream, gat_w, gat_a, VW);
    hipLaunchKernelGGL(lstm_kernel, dim3(128), dim3(512), 0, stream,
                       obs, h0, c0, W_emb, b_emb, W_ih, W_hh, b_ih, b_hh, AH, TAH);
    hipLaunchKernelGGL(gat_kernel,  dim3(512), dim3(256), 0, stream,
                       AH, TAH, VW, ghs, goal, action,
                       W_dist, b_dist, W_gate, b_gate, gat_w, gat_bias, out);
}

// Round 5
// 144.765 us; speedup vs baseline: 1.8004x; 1.3359x over previous
//
#include <hip/hip_runtime.h>

// Problem constants (fixed by setup_inputs)
#define N_PED 2048
#define NGROUP 64
#define NPG 32        // peds per group
#define HDIM 128
#define DIN 64
#define DDIM 64
#define NHEAD 4
#define TOBS 8

typedef __attribute__((ext_vector_type(8))) short bf16x8;
typedef __attribute__((ext_vector_type(4))) float f32x4;

__device__ __forceinline__ float sigm(float x){ return 1.f/(1.f + __expf(-x)); }
__device__ __forceinline__ float tanh_fast(float x){ return 1.f - 2.f/(__expf(2.f*x) + 1.f); }
__device__ __forceinline__ short f2bf(float f){
    unsigned u = __float_as_uint(f);
    unsigned r = (u + 0x7fffu + ((u >> 16) & 1u)) >> 16;   // RNE
    return (short)r;
}
__device__ __forceinline__ float bf2f(unsigned short b){
    return __uint_as_float(((unsigned)b) << 16);
}
__device__ __forceinline__ unsigned pk2(float a, float b){
    return (unsigned)(unsigned short)f2bf(a) | ((unsigned)(unsigned short)f2bf(b) << 16);
}

// ws layout (bytes):
//   AHb  @ 0        : 2048*128 ushort (bf16)   524288
//   TAHb @ 524288   : 2048*128 ushort          524288
//   VW   @ 1048576  : 1024 f32 (V | W1)          4096
//   Gf   @ 1052672  : W_gate B-frags 16*64*8 bf16   16384
//   Wf   @ 1069056  : gat_w  B-frags 128*64*8 bf16 131072
#define WS_AHB   0
#define WS_TAHB  524288
#define WS_VW    1048576
#define WS_GF    1052672
#define WS_WF    1069056

// ---------------------------------------------------------------------------
// prep: V[h][f] = w[h][f]·a2, W1[h][f] = w[h][f]·a1  (fp32 into VW)
// ---------------------------------------------------------------------------
__global__ __launch_bounds__(256) void prep_kernel(const float* __restrict__ gat_w,
                                                   const float* __restrict__ gat_a,
                                                   float* __restrict__ VW) {
    __shared__ float sa[2*HDIM];
    __shared__ float red[32][8][2];
    const int tid = threadIdx.x;
    if (tid < 256) sa[tid] = gat_a[tid];
    __syncthreads();
    const int rl = tid >> 3, ch = tid & 7;
    const int row = blockIdx.x*32 + rl;          // row = h*128 + f
    const float* rp = gat_w + (size_t)row*HDIM + ch*16;
    float v = 0.f, w1 = 0.f;
    #pragma unroll
    for (int e = 0; e < 16; ++e) {
        float wv = rp[e];
        v  += wv * sa[HDIM + ch*16 + e];
        w1 += wv * sa[ch*16 + e];
    }
    red[rl][ch][0] = v; red[rl][ch][1] = w1;
    __syncthreads();
    if (ch == 0) {
        float sv = 0.f, sw = 0.f;
        #pragma unroll
        for (int e = 0; e < 8; ++e) { sv += red[rl][e][0]; sw += red[rl][e][1]; }
        VW[row]       = sv;
        VW[512 + row] = sw;
    }
}

// ---------------------------------------------------------------------------
// pack: build MFMA B-fragments (bf16) for W_gate (Gf: kt<2, nt<8) and
// wcat = stacked gat_w (Wf: kt<16, nt<8).  B[k][n]: lane L holds n=L&15,
// k = (L>>4)*8 + j.  Record = 8 bf16 = 16 B at frag*1024 + L*16.
// ---------------------------------------------------------------------------
__global__ __launch_bounds__(512) void pack_kernel(const float* __restrict__ W_gate,
                                                   const float* __restrict__ gat_w,
                                                   unsigned char* __restrict__ ws) {
    const int id = blockIdx.x*512 + threadIdx.x;
    if (id >= 9216) return;
    uint4* Gf4 = reinterpret_cast<uint4*>(ws + WS_GF);
    uint4* Wf4 = reinterpret_cast<uint4*>(ws + WS_WF);
    if (id < 1024) {
        const int fid = id >> 6, L = id & 63;
        const int kt = fid >> 3, nt = fid & 7;
        const int q = L >> 4, ln = L & 15;
        float v[8];
        #pragma unroll
        for (int j = 0; j < 8; ++j)
            v[j] = W_gate[(size_t)(kt*32 + q*8 + j)*HDIM + nt*16 + ln];
        Gf4[id] = uint4{ pk2(v[0],v[1]), pk2(v[2],v[3]), pk2(v[4],v[5]), pk2(v[6],v[7]) };
    } else {
        const int id2 = id - 1024;
        const int fid = id2 >> 6, L = id2 & 63;
        const int kt = fid >> 3, nt = fid & 7;
        const int q = L >> 4, ln = L & 15;
        float v[8];
        #pragma unroll
        for (int j = 0; j < 8; ++j) {
            int F = kt*32 + q*8 + j;               // F = h*128 + f
            v[j] = gat_w[(size_t)(F >> 7)*16384 + (size_t)(F & 127)*HDIM + nt*16 + ln];
        }
        Wf4[id2] = uint4{ pk2(v[0],v[1]), pk2(v[2],v[3]), pk2(v[4],v[5]), pk2(v[6],v[7]) };
    }
}

// ---------------------------------------------------------------------------
// LSTM via MFMA bf16 (unchanged structure from R4; outputs now bf16)
// ---------------------------------------------------------------------------
#define KPAD 216
__global__ __launch_bounds__(512) void lstm_kernel(
    const float* __restrict__ obs, const float* __restrict__ h0,
    const float* __restrict__ c0,  const float* __restrict__ W_emb,
    const float* __restrict__ b_emb, const float* __restrict__ W_ih,
    const float* __restrict__ W_hh,  const float* __restrict__ b_ih,
    const float* __restrict__ b_hh,
    unsigned short* __restrict__ AHb, unsigned short* __restrict__ TAHb)
{
    __shared__ short Xl[16][KPAD];
    __shared__ float sEmb[192];

    const int tid  = threadIdx.x;
    const int ped0 = blockIdx.x * 16;
    const int w    = tid >> 6;
    const int lane = tid & 63;
    const int q    = lane >> 4;
    const int ln   = lane & 15;
    const int u    = w*16 + ln;

    if (tid < 192) sEmb[tid] = (tid < 128) ? W_emb[tid] : b_emb[tid - 128];

    bf16x8 bfr[4][6];
    #pragma unroll
    for (int idx = 0; idx < 4; ++idx) {
        const int n = idx*128 + u;
        #pragma unroll
        for (int kt = 0; kt < 6; ++kt) {
            const float* src = (kt < 2) ? (W_ih + (size_t)n*DIN  + kt*32 + q*8)
                                        : (W_hh + (size_t)n*HDIM + (kt-2)*32 + q*8);
            bf16x8 b;
            #pragma unroll
            for (int j = 0; j < 8; ++j) b[j] = f2bf(src[j]);
            bfr[idx][kt] = b;
        }
    }
    float bsv[4];
    #pragma unroll
    for (int idx = 0; idx < 4; ++idx) bsv[idx] = b_ih[idx*128 + u] + b_hh[idx*128 + u];

    float c_st[4];
    #pragma unroll
    for (int reg = 0; reg < 4; ++reg)
        c_st[reg] = c0[(size_t)(ped0 + q*4 + reg)*HDIM + u];

    #pragma unroll
    for (int reg = 0; reg < 4; ++reg)
        Xl[q*4 + reg][64 + u] = f2bf(h0[(size_t)(ped0 + q*4 + reg)*HDIM + u]);
    {
        const int ped = tid >> 5, d0 = (tid & 31)*2;
        const float2 ob = reinterpret_cast<const float2*>(obs)[(size_t)(ped0 + ped)];
        float x0 = fmaxf(ob.x*sEmb[d0]   + ob.y*sEmb[64+d0]   + sEmb[128+d0],   0.f);
        float x1 = fmaxf(ob.x*sEmb[d0+1] + ob.y*sEmb[64+d0+1] + sEmb[128+d0+1], 0.f);
        *reinterpret_cast<unsigned*>(&Xl[ped][d0]) = pk2(x0, x1);
    }
    __syncthreads();

    float hval[4];
    for (int t = 0; t < TOBS; ++t) {
        bf16x8 afr[6];
        #pragma unroll
        for (int kt = 0; kt < 6; ++kt)
            afr[kt] = *reinterpret_cast<const bf16x8*>(&Xl[ln][kt*32 + q*8]);

        f32x4 acc[4];
        #pragma unroll
        for (int idx = 0; idx < 4; ++idx) {
            f32x4 a = { bsv[idx], bsv[idx], bsv[idx], bsv[idx] };
            #pragma unroll
            for (int kt = 0; kt < 6; ++kt)
                a = __builtin_amdgcn_mfma_f32_16x16x32_bf16(afr[kt], bfr[idx][kt], a, 0, 0, 0);
            acc[idx] = a;
        }
        #pragma unroll
        for (int reg = 0; reg < 4; ++reg) {
            float c = sigm(acc[1][reg])*c_st[reg] + sigm(acc[0][reg])*tanh_fast(acc[2][reg]);
            c_st[reg] = c;
            hval[reg] = sigm(acc[3][reg])*tanh_fast(c);
        }
        __syncthreads();

        if (t < TOBS-1) {
            #pragma unroll
            for (int reg = 0; reg < 4; ++reg)
                Xl[q*4 + reg][64 + u] = f2bf(hval[reg]);
            {
                const int ped = tid >> 5, d0 = (tid & 31)*2;
                const float2 ob = reinterpret_cast<const float2*>(obs)[(size_t)((t+1)*N_PED + ped0 + ped)];
                float x0 = fmaxf(ob.x*sEmb[d0]   + ob.y*sEmb[64+d0]   + sEmb[128+d0],   0.f);
                float x1 = fmaxf(ob.x*sEmb[d0+1] + ob.y*sEmb[64+d0+1] + sEmb[128+d0+1], 0.f);
                *reinterpret_cast<unsigned*>(&Xl[ped][d0]) = pk2(x0, x1);
            }
            __syncthreads();
        }
    }

    #pragma unroll
    for (int reg = 0; reg < 4; ++reg) {
        const size_t off = (size_t)(ped0 + q*4 + reg)*HDIM + u;
        AHb[off]  = (unsigned short)f2bf(hval[reg]);
        TAHb[off] = (unsigned short)f2bf(tanh_fast(hval[reg]));
    }
}

// ---------------------------------------------------------------------------
// GAT, MFMA edition. 512 blocks x 256 thr (4 waves). Block = (group, 4 rows),
// processed in 2 halves of 2 rows. Self-row trick: sGAb[r][i] := gh so the
// eye-term, the ppd projection, and the alpha-weighted sum all unify.
// LDS = 51,328 B -> 3 blocks/CU.
// ---------------------------------------------------------------------------
__global__ __launch_bounds__(256) void gat_kernel(
    const unsigned short* __restrict__ AHb,
    const unsigned short* __restrict__ TAHb,
    const float* __restrict__ VW,
    const unsigned char* __restrict__ ws,     // Gf/Wf frags
    const float* __restrict__ ghs,
    const float* __restrict__ goal,
    const float* __restrict__ action,
    const float* __restrict__ W_dist,
    const float* __restrict__ b_dist,
    const float* __restrict__ b_gate,
    const float* __restrict__ gat_bias,
    float* __restrict__ out)
{
    __shared__ unsigned short sGAb[80][136];   // 21760: rows 0..63 ga pairs, 64..65 ah, 66..79 junk
    __shared__ unsigned short sTAHb[32][136];  //  8704
    __shared__ unsigned short st1b[64][72];    //  9216
    __shared__ unsigned short sU[4][520];      //  4160  ucat[r][F]
    __shared__ float sAl[2][4][34];            //  1088
    __shared__ float sPj[80][8];               //  2560
    __shared__ float sWd[8][64];               //  2048
    __shared__ float sbd[64];                  //   256
    __shared__ float sbg[128];                 //   512
    __shared__ float sgb[128];                 //   512
    __shared__ float sAC[32][2], sGL[32][2];   //   512

    const int tid = threadIdx.x;
    const int g   = blockIdx.x >> 3;
    const int i0  = (blockIdx.x & 7) * 4;
    const int p0  = g * NPG;
    const int w   = tid >> 6;
    const int L   = tid & 63;
    const int q   = L >> 4;
    const int ln  = L & 15;

    const bf16x8* Gf8 = reinterpret_cast<const bf16x8*>(ws + WS_GF);
    const bf16x8* Wf8 = reinterpret_cast<const bf16x8*>(ws + WS_WF);

    // ---- stage ----
    for (int s = tid; s < 512; s += 256) {     // sTAHb (32 rows x 128, 16B chunks)
        int j = s >> 4, c = s & 15;
        *reinterpret_cast<uint4*>(&sTAHb[j][c*8]) =
            *reinterpret_cast<const uint4*>(&TAHb[(size_t)(p0 + j)*HDIM + c*8]);
    }
    if (tid < 128) {
        sbg[tid] = b_gate[tid];
        sgb[tid] = gat_bias[tid];
    } else if (tid < 192) {
        sbd[tid-128] = b_dist[tid-128];
    } else {
        int j = tid - 192;                     // 0..63 -> 32 peds x (ac|gl)
        int pd = j & 31;
        if (j < 32) { const float2 a = reinterpret_cast<const float2*>(action)[p0+pd];
                      sAC[pd][0]=a.x; sAC[pd][1]=a.y; }
        else        { const float2 gl = reinterpret_cast<const float2*>(goal)[p0+pd];
                      sGL[pd][0]=gl.x; sGL[pd][1]=gl.y; }
    }
    if (tid < 256) {
        int rr = tid >> 6, k = tid & 63;       // sWd[8][64] from W_dist (8,64)
        sWd[rr][k]   = W_dist[rr*64 + k];
        sWd[rr+4][k] = W_dist[(rr+4)*64 + k];
    }

    // Vf: B[k=f][n]: n<4 -> V[n], 4<=n<8 -> W1[n-4], else 0  (4 kt frags)
    bf16x8 vf[4];
    #pragma unroll
    for (int kt = 0; kt < 4; ++kt) {
        bf16x8 b;
        #pragma unroll
        for (int j = 0; j < 8; ++j) {
            int k = kt*32 + q*8 + j;
            float v = 0.f;
            if (ln < 4)      v = VW[ln*HDIM + k];
            else if (ln < 8) v = VW[512 + (ln-4)*HDIM + k];
            b[j] = f2bf(v);
        }
        vf[kt] = b;
    }
    __syncthreads();

    for (int half = 0; half < 2; ++half) {
        // (a) t1 = relu(dist @ W_dist + b_dist), 64 pairs (m = rh*32+j) x 64 k
        {
            const int k = tid & 63, mg = tid >> 6;
            float base[2];
            #pragma unroll
            for (int rh = 0; rh < 2; ++rh) {
                int i = i0 + half*2 + rh;
                base[rh] = sAC[i][0]*sWd[0][k] + sAC[i][1]*sWd[1][k]
                         + sGL[i][0]*sWd[2][k] + sGL[i][1]*sWd[3][k] + sbd[k];
            }
            #pragma unroll
            for (int mm = 0; mm < 16; ++mm) {
                int m = mg*16 + mm, j = m & 31;
                float v = base[m>>5] + sAC[j][0]*sWd[4][k] + sAC[j][1]*sWd[5][k]
                                     + sGL[j][0]*sWd[6][k] + sGL[j][1]*sWd[7][k];
                st1b[m][k] = (unsigned short)f2bf(fmaxf(v, 0.f));
            }
        }
        __syncthreads();

        // (b) gate MLP layer 2 via MFMA: (64x64)@(64x128), then sigmoid*tanh_ah
        {
            bf16x8 afr[2];
            #pragma unroll
            for (int kt = 0; kt < 2; ++kt)
                afr[kt] = *reinterpret_cast<const bf16x8*>(&st1b[w*16 + ln][kt*32 + q*8]);
            for (int nt = 0; nt < 8; ++nt) {
                float bg = sbg[nt*16 + ln];
                f32x4 a = { bg, bg, bg, bg };
                a = __builtin_amdgcn_mfma_f32_16x16x32_bf16(afr[0], Gf8[(0*8+nt)*64 + L], a, 0, 0, 0);
                a = __builtin_amdgcn_mfma_f32_16x16x32_bf16(afr[1], Gf8[(1*8+nt)*64 + L], a, 0, 0, 0);
                #pragma unroll
                for (int reg = 0; reg < 4; ++reg) {
                    int mrow = w*16 + q*4 + reg;         // pair row
                    int n = nt*16 + ln;
                    float ga = sigm(a[reg]) * bf2f(sTAHb[mrow & 31][n]);
                    sGAb[mrow][n] = (unsigned short)f2bf(ga);
                }
            }
        }
        __syncthreads();

        // self rows := gh ; ah rows (64,65)
        {
            int rh = tid >> 7, f = tid & 127;
            int irow = i0 + half*2 + rh;
            sGAb[rh*32 + irow][f] = (unsigned short)f2bf(ghs[(size_t)(p0 + irow)*HDIM + f]);
            sGAb[64 + rh][f]      = AHb[(size_t)(p0 + irow)*HDIM + f];
        }
        __syncthreads();

        // (c) projections: (80x128)@(128x16 [V|W1|0]) -> sPj
        {
            int nmt = (w == 0) ? 2 : 1;
            for (int e = 0; e < nmt; ++e) {
                int mt = (e == 0) ? w : 4;
                bf16x8 afr;
                f32x4 a = { 0.f, 0.f, 0.f, 0.f };
                #pragma unroll
                for (int kt = 0; kt < 4; ++kt) {
                    afr = *reinterpret_cast<const bf16x8*>(&sGAb[mt*16 + ln][kt*32 + q*8]);
                    a = __builtin_amdgcn_mfma_f32_16x16x32_bf16(afr, vf[kt], a, 0, 0, 0);
                }
                if (ln < 8) {
                    #pragma unroll
                    for (int reg = 0; reg < 4; ++reg)
                        sPj[mt*16 + q*4 + reg][ln] = a[reg];
                }
            }
        }
        __syncthreads();

        // (d) softmax over 33 per (rh,h): 8 threads, x0-shifted exp
        if (tid < 8) {
            int rh = tid >> 2, h = tid & 3;
            float sa_ = sPj[64 + rh][4 + h];
            float x0  = sa_ + sPj[64 + rh][h];          // k=0 (self ah)
            x0 = (x0 < 0.f) ? 0.2f*x0 : x0;
            float sum = 1.f;                             // exp(x0-x0)
            sAl[rh][h][0] = 1.f;
            for (int k = 1; k <= 32; ++k) {
                float x = sa_ + sPj[rh*32 + k - 1][h];
                x = (x < 0.f) ? 0.2f*x : x;
                float e = __expf(x - x0);
                sAl[rh][h][k] = e; sum += e;
            }
            float inv = 1.f/sum;
            for (int k = 0; k <= 32; ++k) sAl[rh][h][k] *= inv;
        }
        __syncthreads();

        // (e) u[h][f] = sum_j alpha_{j+1} * sGAb[rh*32+j][f]  (+ alpha_0*ah)
        {
            int rh = w & 1, ntb = (w >> 1) * 4;
            int r  = half*2 + rh;
            bf16x8 afr;                                   // A[m=h][k=j] = alpha
            #pragma unroll
            for (int jj = 0; jj < 8; ++jj)
                afr[jj] = f2bf(sAl[rh][ln & 3][1 + q*8 + jj]);
            for (int t = 0; t < 4; ++t) {
                int nt = ntb + t;
                bf16x8 bfr;
                #pragma unroll
                for (int jj = 0; jj < 8; ++jj)
                    bfr[jj] = (short)sGAb[rh*32 + q*8 + jj][nt*16 + ln];
                f32x4 a = { 0.f, 0.f, 0.f, 0.f };
                a = __builtin_amdgcn_mfma_f32_16x16x32_bf16(afr, bfr, a, 0, 0, 0);
                if (L < 16) {
                    #pragma unroll
                    for (int reg = 0; reg < 4; ++reg) {   // h = reg
                        float uv = a[reg] + sAl[rh][reg][0] * bf2f(sGAb[64 + rh][nt*16 + ln]);
                        sU[r][reg*HDIM + nt*16 + ln] = (unsigned short)f2bf(uv);
                    }
                }
            }
        }
        __syncthreads();
    }

    // (f) out[r] = relu( 0.25 * ucat[r] @ wcat ) + gat_bias : M=4,K=512,N=128
    {
        bf16x8 afr[16];
        #pragma unroll
        for (int kt = 0; kt < 16; ++kt)
            afr[kt] = *reinterpret_cast<const bf16x8*>(&sU[ln & 3][kt*32 + q*8]);
        for (int e = 0; e < 2; ++e) {
            int nt = w*2 + e;
            f32x4 a = { 0.f, 0.f, 0.f, 0.f };
            #pragma unroll
            for (int kt = 0; kt < 16; ++kt)
                a = __builtin_amdgcn_mfma_f32_16x16x32_bf16(afr[kt], Wf8[(kt*8+nt)*64 + L], a, 0, 0, 0);
            if (L < 16) {
                int o = nt*16 + ln;
                #pragma unroll
                for (int reg = 0; reg < 4; ++reg) {       // r = reg
                    float val = fmaxf(a[reg]*0.25f, 0.f) + sgb[o];
                    out[(size_t)(p0 + i0 + reg)*HDIM + o] = val;
                }
            }
        }
    }
}

// ---------------------------------------------------------------------------
extern "C" void kernel_launch(void* const* d_in, const int* in_sizes, int n_in,
                              void* d_out, int out_size, void* d_ws, size_t ws_size,
                              hipStream_t stream) {
    const float* obs      = (const float*)d_in[0];
    const float* ghs      = (const float*)d_in[1];
    const float* goal     = (const float*)d_in[2];
    const float* action   = (const float*)d_in[3];
    const float* h0       = (const float*)d_in[4];
    const float* c0       = (const float*)d_in[5];
    const float* W_emb    = (const float*)d_in[6];
    const float* b_emb    = (const float*)d_in[7];
    const float* W_ih     = (const float*)d_in[8];
    const float* W_hh     = (const float*)d_in[9];
    const float* b_ih     = (const float*)d_in[10];
    const float* b_hh     = (const float*)d_in[11];
    const float* W_dist   = (const float*)d_in[12];
    const float* b_dist   = (const float*)d_in[13];
    const float* W_gate   = (const float*)d_in[14];
    const float* b_gate   = (const float*)d_in[15];
    const float* gat_w    = (const float*)d_in[16];
    const float* gat_a    = (const float*)d_in[17];
    const float* gat_bias = (const float*)d_in[18];

    unsigned char* ws = (unsigned char*)d_ws;
    unsigned short* AHb  = (unsigned short*)(ws + WS_AHB);
    unsigned short* TAHb = (unsigned short*)(ws + WS_TAHB);
    float* VW            = (float*)(ws + WS_VW);
    float* out = (float*)d_out;

    hipLaunchKernelGGL(prep_kernel, dim3(16),  dim3(256), 0, stream, gat_w, gat_a, VW);
    hipLaunchKernelGGL(pack_kernel, dim3(18),  dim3(512), 0, stream, W_gate, gat_w, ws);
    hipLaunchKernelGGL(lstm_kernel, dim3(128), dim3(512), 0, stream,
                       obs, h0, c0, W_emb, b_emb, W_ih, W_hh, b_ih, b_hh, AHb, TAHb);
    hipLaunchKernelGGL(gat_kernel,  dim3(512), dim3(256), 0, stream,
                       AHb, TAHb, VW, ws, ghs, goal, action,
                       W_dist, b_dist, b_gate, gat_bias, out);
}

// Round 6
// 137.133 us; speedup vs baseline: 1.9006x; 1.0557x over previous
//
#include <hip/hip_runtime.h>

// Problem constants (fixed by setup_inputs)
#define N_PED 2048
#define NGROUP 64
#define NPG 32        // peds per group
#define HDIM 128
#define DIN 64
#define DDIM 64
#define NHEAD 4
#define TOBS 8

typedef __attribute__((ext_vector_type(8))) short bf16x8;
typedef __attribute__((ext_vector_type(4))) float f32x4;

__device__ __forceinline__ float sigm(float x){
    return __builtin_amdgcn_rcpf(1.f + __expf(-x));
}
__device__ __forceinline__ float tanh_fast(float x){
    return 1.f - 2.f*__builtin_amdgcn_rcpf(__expf(2.f*x) + 1.f);
}
__device__ __forceinline__ short f2bf(float f){
    unsigned u = __float_as_uint(f);
    unsigned r = (u + 0x7fffu + ((u >> 16) & 1u)) >> 16;   // RNE
    return (short)r;
}
__device__ __forceinline__ float bf2f(unsigned short b){
    return __uint_as_float(((unsigned)b) << 16);
}
__device__ __forceinline__ unsigned pk2(float a, float b){
    return (unsigned)(unsigned short)f2bf(a) | ((unsigned)(unsigned short)f2bf(b) << 16);
}

// ws layout (bytes):
//   AHb  @ 0        : 2048*128 ushort (bf16)   524288
//   TAHb @ 524288   : 2048*128 ushort          524288
//   VW   @ 1048576  : 1024 f32 (V | W1)          4096
//   Gf   @ 1052672  : W_gate B-frags 16*64*8 bf16   16384
//   Wf   @ 1069056  : gat_w  B-frags 128*64*8 bf16 131072
#define WS_AHB   0
#define WS_TAHB  524288
#define WS_VW    1048576
#define WS_GF    1052672
#define WS_WF    1069056

// ---------------------------------------------------------------------------
// prep+pack merged. Blocks 0..15: V/W1 projections (prep). Blocks 16..33:
// MFMA B-fragment packing for W_gate (Gf) and stacked gat_w (Wf).
// ---------------------------------------------------------------------------
__global__ __launch_bounds__(512) void prep_pack_kernel(
    const float* __restrict__ gat_w, const float* __restrict__ gat_a,
    const float* __restrict__ W_gate, unsigned char* __restrict__ ws)
{
    const int tid = threadIdx.x;
    if (blockIdx.x < 16) {
        // ---- prep: V[h][f] = w[h][f]·a2, W1[h][f] = w[h][f]·a1 ----
        __shared__ float sa[2*HDIM];
        __shared__ float red[32][8][2];
        float* VW = (float*)(ws + WS_VW);
        if (tid < 256) sa[tid] = gat_a[tid];
        __syncthreads();
        const int rl = (tid & 255) >> 3, ch = tid & 7;
        const int row = blockIdx.x*32 + rl;          // row = h*128 + f
        if (tid < 256) {
            const float* rp = gat_w + (size_t)row*HDIM + ch*16;
            float v = 0.f, w1 = 0.f;
            #pragma unroll
            for (int e = 0; e < 16; ++e) {
                float wv = rp[e];
                v  += wv * sa[HDIM + ch*16 + e];
                w1 += wv * sa[ch*16 + e];
            }
            red[rl][ch][0] = v; red[rl][ch][1] = w1;
        }
        __syncthreads();
        if (tid < 256 && ch == 0) {
            float sv = 0.f, sw = 0.f;
            #pragma unroll
            for (int e = 0; e < 8; ++e) { sv += red[rl][e][0]; sw += red[rl][e][1]; }
            VW[row]       = sv;
            VW[512 + row] = sw;
        }
    } else {
        // ---- pack: B[k][n] frags, lane L: n = L&15, k = (L>>4)*8 + j ----
        const int id = (blockIdx.x - 16)*512 + tid;
        if (id >= 9216) return;
        uint4* Gf4 = reinterpret_cast<uint4*>(ws + WS_GF);
        uint4* Wf4 = reinterpret_cast<uint4*>(ws + WS_WF);
        if (id < 1024) {
            const int fid = id >> 6, L = id & 63;
            const int kt = fid >> 3, nt = fid & 7;
            const int q = L >> 4, ln = L & 15;
            float v[8];
            #pragma unroll
            for (int j = 0; j < 8; ++j)
                v[j] = W_gate[(size_t)(kt*32 + q*8 + j)*HDIM + nt*16 + ln];
            Gf4[id] = uint4{ pk2(v[0],v[1]), pk2(v[2],v[3]), pk2(v[4],v[5]), pk2(v[6],v[7]) };
        } else {
            const int id2 = id - 1024;
            const int fid = id2 >> 6, L = id2 & 63;
            const int kt = fid >> 3, nt = fid & 7;
            const int q = L >> 4, ln = L & 15;
            float v[8];
            #pragma unroll
            for (int j = 0; j < 8; ++j) {
                int F = kt*32 + q*8 + j;               // F = h*128 + f
                v[j] = gat_w[(size_t)(F >> 7)*16384 + (size_t)(F & 127)*HDIM + nt*16 + ln];
            }
            Wf4[id2] = uint4{ pk2(v[0],v[1]), pk2(v[2],v[3]), pk2(v[4],v[5]), pk2(v[6],v[7]) };
        }
    }
}

// ---------------------------------------------------------------------------
// LSTM via MFMA bf16, v3: 256 blocks x 512 thr, 8 peds/block (M rows 8..15
// mirror 0..7 -> full grid coverage, 1 block/CU on all 256 CUs).
// Double-buffered X (1 barrier/step), obs-embed prefetched before the MFMA
// chain. Wave w owns n-tiles {w,w+8,w+16,w+24} so lane accs are i/f/g/o of
// (ped, unit) -> cell update in registers. Weights in 96 VGPRs (t-invariant).
// ---------------------------------------------------------------------------
#define KPAD 216
__global__ __launch_bounds__(512) void lstm_kernel(
    const float* __restrict__ obs, const float* __restrict__ h0,
    const float* __restrict__ c0,  const float* __restrict__ W_emb,
    const float* __restrict__ b_emb, const float* __restrict__ W_ih,
    const float* __restrict__ W_hh,  const float* __restrict__ b_ih,
    const float* __restrict__ b_hh,
    unsigned short* __restrict__ AHb, unsigned short* __restrict__ TAHb)
{
    __shared__ short Xl[2][16][KPAD];
    __shared__ float sEmb[192];

    const int tid  = threadIdx.x;
    const int ped0 = blockIdx.x * 8;
    const int w    = tid >> 6;
    const int lane = tid & 63;
    const int q    = lane >> 4;
    const int ln   = lane & 15;
    const int u    = w*16 + ln;

    if (tid < 192) sEmb[tid] = (tid < 128) ? W_emb[tid] : b_emb[tid - 128];

    bf16x8 bfr[4][6];
    #pragma unroll
    for (int idx = 0; idx < 4; ++idx) {
        const int n = idx*128 + u;
        #pragma unroll
        for (int kt = 0; kt < 6; ++kt) {
            const float* src = (kt < 2) ? (W_ih + (size_t)n*DIN  + kt*32 + q*8)
                                        : (W_hh + (size_t)n*HDIM + (kt-2)*32 + q*8);
            bf16x8 b;
            #pragma unroll
            for (int j = 0; j < 8; ++j) b[j] = f2bf(src[j]);
            bfr[idx][kt] = b;
        }
    }
    float bsv[4];
    #pragma unroll
    for (int idx = 0; idx < 4; ++idx) bsv[idx] = b_ih[idx*128 + u] + b_hh[idx*128 + u];

    float c_st[4];
    #pragma unroll
    for (int reg = 0; reg < 4; ++reg)
        c_st[reg] = c0[(size_t)(ped0 + ((q*4 + reg) & 7))*HDIM + u];

    // stage h0 (mirrored rows) + x_0 into buffer 0
    #pragma unroll
    for (int reg = 0; reg < 4; ++reg)
        Xl[0][q*4 + reg][64 + u] = f2bf(h0[(size_t)(ped0 + ((q*4 + reg) & 7))*HDIM + u]);
    {
        const int pr = tid >> 5, d0 = (tid & 31)*2;    // pr 0..15 (mirror rows)
        const float2 ob = reinterpret_cast<const float2*>(obs)[(size_t)(ped0 + (pr & 7))];
        float x0 = fmaxf(ob.x*sEmb[d0]   + ob.y*sEmb[64+d0]   + sEmb[128+d0],   0.f);
        float x1 = fmaxf(ob.x*sEmb[d0+1] + ob.y*sEmb[64+d0+1] + sEmb[128+d0+1], 0.f);
        *reinterpret_cast<unsigned*>(&Xl[0][pr][d0]) = pk2(x0, x1);
    }
    __syncthreads();

    float hval[4];
    for (int t = 0; t < TOBS; ++t) {
        const int cur = t & 1, nxt = cur ^ 1;

        // prefetch x_{t+1} into the other buffer (independent of MFMA chain)
        if (t < TOBS-1) {
            const int pr = tid >> 5, d0 = (tid & 31)*2;
            const float2 ob = reinterpret_cast<const float2*>(obs)[(size_t)((t+1)*N_PED + ped0 + (pr & 7))];
            float x0 = fmaxf(ob.x*sEmb[d0]   + ob.y*sEmb[64+d0]   + sEmb[128+d0],   0.f);
            float x1 = fmaxf(ob.x*sEmb[d0+1] + ob.y*sEmb[64+d0+1] + sEmb[128+d0+1], 0.f);
            *reinterpret_cast<unsigned*>(&Xl[nxt][pr][d0]) = pk2(x0, x1);
        }

        bf16x8 afr[6];
        #pragma unroll
        for (int kt = 0; kt < 6; ++kt)
            afr[kt] = *reinterpret_cast<const bf16x8*>(&Xl[cur][ln][kt*32 + q*8]);

        f32x4 acc[4];
        #pragma unroll
        for (int idx = 0; idx < 4; ++idx) {
            f32x4 a = { bsv[idx], bsv[idx], bsv[idx], bsv[idx] };
            #pragma unroll
            for (int kt = 0; kt < 6; ++kt)
                a = __builtin_amdgcn_mfma_f32_16x16x32_bf16(afr[kt], bfr[idx][kt], a, 0, 0, 0);
            acc[idx] = a;
        }
        #pragma unroll
        for (int reg = 0; reg < 4; ++reg) {
            float c = sigm(acc[1][reg])*c_st[reg] + sigm(acc[0][reg])*tanh_fast(acc[2][reg]);
            c_st[reg] = c;
            hval[reg] = sigm(acc[3][reg])*tanh_fast(c);
        }

        if (t < TOBS-1) {
            #pragma unroll
            for (int reg = 0; reg < 4; ++reg)
                Xl[nxt][q*4 + reg][64 + u] = f2bf(hval[reg]);
            __syncthreads();
        }
    }

    if (q < 2) {
        #pragma unroll
        for (int reg = 0; reg < 4; ++reg) {
            const size_t off = (size_t)(ped0 + q*4 + reg)*HDIM + u;
            AHb[off]  = (unsigned short)f2bf(hval[reg]);
            TAHb[off] = (unsigned short)f2bf(tanh_fast(hval[reg]));
        }
    }
}

// ---------------------------------------------------------------------------
// GAT, MFMA edition (unchanged from R5). 512 blocks x 256 thr.
// ---------------------------------------------------------------------------
__global__ __launch_bounds__(256) void gat_kernel(
    const unsigned short* __restrict__ AHb,
    const unsigned short* __restrict__ TAHb,
    const float* __restrict__ VW,
    const unsigned char* __restrict__ ws,     // Gf/Wf frags
    const float* __restrict__ ghs,
    const float* __restrict__ goal,
    const float* __restrict__ action,
    const float* __restrict__ W_dist,
    const float* __restrict__ b_dist,
    const float* __restrict__ b_gate,
    const float* __restrict__ gat_bias,
    float* __restrict__ out)
{
    __shared__ unsigned short sGAb[80][136];
    __shared__ unsigned short sTAHb[32][136];
    __shared__ unsigned short st1b[64][72];
    __shared__ unsigned short sU[4][520];
    __shared__ float sAl[2][4][34];
    __shared__ float sPj[80][8];
    __shared__ float sWd[8][64];
    __shared__ float sbd[64];
    __shared__ float sbg[128];
    __shared__ float sgb[128];
    __shared__ float sAC[32][2], sGL[32][2];

    const int tid = threadIdx.x;
    const int g   = blockIdx.x >> 3;
    const int i0  = (blockIdx.x & 7) * 4;
    const int p0  = g * NPG;
    const int w   = tid >> 6;
    const int L   = tid & 63;
    const int q   = L >> 4;
    const int ln  = L & 15;

    const bf16x8* Gf8 = reinterpret_cast<const bf16x8*>(ws + WS_GF);
    const bf16x8* Wf8 = reinterpret_cast<const bf16x8*>(ws + WS_WF);

    for (int s = tid; s < 512; s += 256) {
        int j = s >> 4, c = s & 15;
        *reinterpret_cast<uint4*>(&sTAHb[j][c*8]) =
            *reinterpret_cast<const uint4*>(&TAHb[(size_t)(p0 + j)*HDIM + c*8]);
    }
    if (tid < 128) {
        sbg[tid] = b_gate[tid];
        sgb[tid] = gat_bias[tid];
    } else if (tid < 192) {
        sbd[tid-128] = b_dist[tid-128];
    } else {
        int j = tid - 192;
        int pd = j & 31;
        if (j < 32) { const float2 a = reinterpret_cast<const float2*>(action)[p0+pd];
                      sAC[pd][0]=a.x; sAC[pd][1]=a.y; }
        else        { const float2 gl = reinterpret_cast<const float2*>(goal)[p0+pd];
                      sGL[pd][0]=gl.x; sGL[pd][1]=gl.y; }
    }
    if (tid < 256) {
        int rr = tid >> 6, k = tid & 63;
        sWd[rr][k]   = W_dist[rr*64 + k];
        sWd[rr+4][k] = W_dist[(rr+4)*64 + k];
    }

    bf16x8 vf[4];
    #pragma unroll
    for (int kt = 0; kt < 4; ++kt) {
        bf16x8 b;
        #pragma unroll
        for (int j = 0; j < 8; ++j) {
            int k = kt*32 + q*8 + j;
            float v = 0.f;
            if (ln < 4)      v = VW[ln*HDIM + k];
            else if (ln < 8) v = VW[512 + (ln-4)*HDIM + k];
            b[j] = f2bf(v);
        }
        vf[kt] = b;
    }
    __syncthreads();

    for (int half = 0; half < 2; ++half) {
        // (a) t1 = relu(dist @ W_dist + b_dist)
        {
            const int k = tid & 63, mg = tid >> 6;
            float base[2];
            #pragma unroll
            for (int rh = 0; rh < 2; ++rh) {
                int i = i0 + half*2 + rh;
                base[rh] = sAC[i][0]*sWd[0][k] + sAC[i][1]*sWd[1][k]
                         + sGL[i][0]*sWd[2][k] + sGL[i][1]*sWd[3][k] + sbd[k];
            }
            #pragma unroll
            for (int mm = 0; mm < 16; ++mm) {
                int m = mg*16 + mm, j = m & 31;
                float v = base[m>>5] + sAC[j][0]*sWd[4][k] + sAC[j][1]*sWd[5][k]
                                     + sGL[j][0]*sWd[6][k] + sGL[j][1]*sWd[7][k];
                st1b[m][k] = (unsigned short)f2bf(fmaxf(v, 0.f));
            }
        }
        __syncthreads();

        // (b) gate MLP layer 2 via MFMA + sigmoid*tanh_ah
        {
            bf16x8 afr[2];
            #pragma unroll
            for (int kt = 0; kt < 2; ++kt)
                afr[kt] = *reinterpret_cast<const bf16x8*>(&st1b[w*16 + ln][kt*32 + q*8]);
            for (int nt = 0; nt < 8; ++nt) {
                float bg = sbg[nt*16 + ln];
                f32x4 a = { bg, bg, bg, bg };
                a = __builtin_amdgcn_mfma_f32_16x16x32_bf16(afr[0], Gf8[(0*8+nt)*64 + L], a, 0, 0, 0);
                a = __builtin_amdgcn_mfma_f32_16x16x32_bf16(afr[1], Gf8[(1*8+nt)*64 + L], a, 0, 0, 0);
                #pragma unroll
                for (int reg = 0; reg < 4; ++reg) {
                    int mrow = w*16 + q*4 + reg;
                    int n = nt*16 + ln;
                    float ga = sigm(a[reg]) * bf2f(sTAHb[mrow & 31][n]);
                    sGAb[mrow][n] = (unsigned short)f2bf(ga);
                }
            }
        }
        __syncthreads();

        // self rows := gh ; ah rows (64,65)
        {
            int rh = tid >> 7, f = tid & 127;
            int irow = i0 + half*2 + rh;
            sGAb[rh*32 + irow][f] = (unsigned short)f2bf(ghs[(size_t)(p0 + irow)*HDIM + f]);
            sGAb[64 + rh][f]      = AHb[(size_t)(p0 + irow)*HDIM + f];
        }
        __syncthreads();

        // (c) projections onto [V|W1]
        {
            int nmt = (w == 0) ? 2 : 1;
            for (int e = 0; e < nmt; ++e) {
                int mt = (e == 0) ? w : 4;
                bf16x8 afr;
                f32x4 a = { 0.f, 0.f, 0.f, 0.f };
                #pragma unroll
                for (int kt = 0; kt < 4; ++kt) {
                    afr = *reinterpret_cast<const bf16x8*>(&sGAb[mt*16 + ln][kt*32 + q*8]);
                    a = __builtin_amdgcn_mfma_f32_16x16x32_bf16(afr, vf[kt], a, 0, 0, 0);
                }
                if (ln < 8) {
                    #pragma unroll
                    for (int reg = 0; reg < 4; ++reg)
                        sPj[mt*16 + q*4 + reg][ln] = a[reg];
                }
            }
        }
        __syncthreads();

        // (d) softmax over 33 per (rh,h)
        if (tid < 8) {
            int rh = tid >> 2, h = tid & 3;
            float sa_ = sPj[64 + rh][4 + h];
            float x0  = sa_ + sPj[64 + rh][h];
            x0 = (x0 < 0.f) ? 0.2f*x0 : x0;
            float sum = 1.f;
            sAl[rh][h][0] = 1.f;
            for (int k = 1; k <= 32; ++k) {
                float x = sa_ + sPj[rh*32 + k - 1][h];
                x = (x < 0.f) ? 0.2f*x : x;
                float e = __expf(x - x0);
                sAl[rh][h][k] = e; sum += e;
            }
            float inv = 1.f/sum;
            for (int k = 0; k <= 32; ++k) sAl[rh][h][k] *= inv;
        }
        __syncthreads();

        // (e) u[h] = alpha-weighted sum
        {
            int rh = w & 1, ntb = (w >> 1) * 4;
            int r  = half*2 + rh;
            bf16x8 afr;
            #pragma unroll
            for (int jj = 0; jj < 8; ++jj)
                afr[jj] = f2bf(sAl[rh][ln & 3][1 + q*8 + jj]);
            for (int t = 0; t < 4; ++t) {
                int nt = ntb + t;
                bf16x8 bfr;
                #pragma unroll
                for (int jj = 0; jj < 8; ++jj)
                    bfr[jj] = (short)sGAb[rh*32 + q*8 + jj][nt*16 + ln];
                f32x4 a = { 0.f, 0.f, 0.f, 0.f };
                a = __builtin_amdgcn_mfma_f32_16x16x32_bf16(afr, bfr, a, 0, 0, 0);
                if (L < 16) {
                    #pragma unroll
                    for (int reg = 0; reg < 4; ++reg) {
                        float uv = a[reg] + sAl[rh][reg][0] * bf2f(sGAb[64 + rh][nt*16 + ln]);
                        sU[r][reg*HDIM + nt*16 + ln] = (unsigned short)f2bf(uv);
                    }
                }
            }
        }
        __syncthreads();
    }

    // (f) out = relu(0.25 * ucat @ wcat) + gat_bias
    {
        bf16x8 afr[16];
        #pragma unroll
        for (int kt = 0; kt < 16; ++kt)
            afr[kt] = *reinterpret_cast<const bf16x8*>(&sU[ln & 3][kt*32 + q*8]);
        for (int e = 0; e < 2; ++e) {
            int nt = w*2 + e;
            f32x4 a = { 0.f, 0.f, 0.f, 0.f };
            #pragma unroll
            for (int kt = 0; kt < 16; ++kt)
                a = __builtin_amdgcn_mfma_f32_16x16x32_bf16(afr[kt], Wf8[(kt*8+nt)*64 + L], a, 0, 0, 0);
            if (L < 16) {
                int o = nt*16 + ln;
                #pragma unroll
                for (int reg = 0; reg < 4; ++reg) {
                    float val = fmaxf(a[reg]*0.25f, 0.f) + sgb[o];
                    out[(size_t)(p0 + i0 + reg)*HDIM + o] = val;
                }
            }
        }
    }
}

// ---------------------------------------------------------------------------
extern "C" void kernel_launch(void* const* d_in, const int* in_sizes, int n_in,
                              void* d_out, int out_size, void* d_ws, size_t ws_size,
                              hipStream_t stream) {
    const float* obs      = (const float*)d_in[0];
    const float* ghs      = (const float*)d_in[1];
    const float* goal     = (const float*)d_in[2];
    const float* action   = (const float*)d_in[3];
    const float* h0       = (const float*)d_in[4];
    const float* c0       = (const float*)d_in[5];
    const float* W_emb    = (const float*)d_in[6];
    const float* b_emb    = (const float*)d_in[7];
    const float* W_ih     = (const float*)d_in[8];
    const float* W_hh     = (const float*)d_in[9];
    const float* b_ih     = (const float*)d_in[10];
    const float* b_hh     = (const float*)d_in[11];
    const float* W_dist   = (const float*)d_in[12];
    const float* b_dist   = (const float*)d_in[13];
    const float* W_gate   = (const float*)d_in[14];
    const float* b_gate   = (const float*)d_in[15];
    const float* gat_w    = (const float*)d_in[16];
    const float* gat_a    = (const float*)d_in[17];
    const float* gat_bias = (const float*)d_in[18];

    unsigned char* ws = (unsigned char*)d_ws;
    unsigned short* AHb  = (unsigned short*)(ws + WS_AHB);
    unsigned short* TAHb = (unsigned short*)(ws + WS_TAHB);
    float* VW            = (float*)(ws + WS_VW);
    float* out = (float*)d_out;

    hipLaunchKernelGGL(prep_pack_kernel, dim3(34), dim3(512), 0, stream,
                       gat_w, gat_a, W_gate, ws);
    hipLaunchKernelGGL(lstm_kernel, dim3(256), dim3(512), 0, stream,
                       obs, h0, c0, W_emb, b_emb, W_ih, W_hh, b_ih, b_hh, AHb, TAHb);
    hipLaunchKernelGGL(gat_kernel,  dim3(512), dim3(256), 0, stream,
                       AHb, TAHb, VW, ws, ghs, goal, action,
                       W_dist, b_dist, b_gate, gat_bias, out);
}